// Round 9
// baseline (945.006 us; speedup 1.0000x reference)
//
#include <hip/hip_runtime.h>
#include <math.h>

// -----------------------------------------------------------------------------
// DFSPH divergence-solve, block-aggregated binning, i-side deferred to reduce.
//   pre:    per-particle 32B {p, r=m/aa, aa, aa^2/m | vx,vy,ax,ay}; zero cursors.
//   bin:    2048 edges/block, software-pipelined:
//             phase 1: stream nbr/rad/dirs (nontemporal) into regs, rank
//                      per-bucket in LDS.
//             phase 2a: issue ALL pre2[j] gathers BEFORE the barrier.
//             claim:   one global cursor atomic per (block,bucket), 1/cacheline.
//             phase 2b: compute, CACHED store of ONE 32B record/edge:
//                      {c0=aa*gx, c1=aa*gy, c2=aa2m*g2, r | pj, q5, q6, li}.
//   reduce: PB=512/bucket, 16.4 KB LDS. Main loop loads 8 edges (16 float4)
//           into register arrays BEFORE any LDS atomic (forces 16 loads in
//           flight; round-8's VGPR=24 showed the scheduler serialized when
//           atomics interleaved). Out-of-range lanes clamp the index and scale
//           contributions by 0 (atomicAdd of 0 is a no-op) -> no serial tail.
//           i-side v/a corrections are linear -> applied once per particle at
//           slice-write. No global float atomics.
//   fin:    sum SLICES=4 slices, alpha, write [N,5].
// Fallback (tiny ws): direct global float atomics.
// -----------------------------------------------------------------------------

#define PB        512
#define PB_SHIFT  9
#define SLICES    4
#define CSTRIDE   16      // ints per cursor -> 64B, one cacheline each
#define BIN_EPT   8       // edges per thread in bin
#define RED_EPT   8       // edges per thread per reduce iteration

typedef float v2f __attribute__((ext_vector_type(2)));

static inline size_t align256(size_t x) { return (x + 255) & ~(size_t)255; }

__global__ __launch_bounds__(256) void pre_kernel(
    const float*  __restrict__ area,
    const float*  __restrict__ actualArea,
    const float*  __restrict__ restDensity,
    const float*  __restrict__ density,
    const float*  __restrict__ pressure2,
    const float2* __restrict__ vel,
    const float2* __restrict__ accel,
    float4* __restrict__ pre2,
    int*    __restrict__ cursor, int ncursor,
    float*  __restrict__ accz, int nacc,
    int n) {
    int t = blockIdx.x * blockDim.x + threadIdx.x;
    if (t < ncursor) cursor[t] = 0;
    for (int k = t; k < nacc; k += gridDim.x * blockDim.x) accz[k] = 0.f;
    if (t >= n) return;
    float m  = area[t] * restDensity[t];
    float dr = density[t] * restDensity[t];
    float p  = pressure2[t] / (dr * dr);
    float aa = actualArea[t];
    float2 v  = vel[t];
    float2 ac = accel[t];
    pre2[2 * (size_t)t]     = make_float4(p, m / aa, aa, aa * aa / m);
    pre2[2 * (size_t)t + 1] = make_float4(v.x, v.y, ac.x, ac.y);
}

__global__ __launch_bounds__(256) void bin_kernel(
    const int*    __restrict__ nbr,
    const float*  __restrict__ rad,
    const float2* __restrict__ dirs,
    const float4* __restrict__ pre2,
    const float*  __restrict__ supp,
    const float*  __restrict__ dtp,
    int*          __restrict__ cursor,
    float4*       __restrict__ pay,
    int cap, int nb, int estart, int eend, int E) {
    __shared__ int lcount[512];
    __shared__ int lbase[512];
    int tid = threadIdx.x;
    for (int k = tid; k < nb; k += 256) lcount[k] = 0;
    __syncthreads();
    int e0 = estart + blockIdx.x * (256 * BIN_EPT) + tid;

    // phase 1: stream everything per-edge into registers, rank per bucket
    int jj[BIN_EPT]; float qq[BIN_EPT]; v2f dd[BIN_EPT]; int pack[BIN_EPT];
#pragma unroll
    for (int k = 0; k < BIN_EPT; ++k) {
        int e = e0 + k * 256;
        pack[k] = -1; jj[k] = 0; qq[k] = 0.f; dd[k] = (v2f){0.f, 0.f};
        if (e < eend) {
            jj[k] = __builtin_nontemporal_load(nbr + E + e);
            qq[k] = __builtin_nontemporal_load(rad + e);
            dd[k] = __builtin_nontemporal_load((const v2f*)dirs + e);
            int i = __builtin_nontemporal_load(nbr + e);
            int b = i >> PB_SHIFT;
            int r = atomicAdd(&lcount[b], 1);
            pack[k] = (b << 22) | ((i & (PB - 1)) << 12) | r;
        }
    }

    // phase 2a: issue ALL gathers before the barrier (latency hides behind
    // the sync + cursor claim; loads depend only on jj[])
    float4 ja[BIN_EPT], jb[BIN_EPT];
#pragma unroll
    for (int k = 0; k < BIN_EPT; ++k) {
        size_t j2 = 2 * (size_t)jj[k];
        ja[k] = pre2[j2];
        jb[k] = pre2[j2 + 1];
    }

    __syncthreads();
    // one global cursor claim per (block,bucket)
    for (int k = tid; k < nb; k += 256) {
        int c = lcount[k];
        lbase[k] = c ? atomicAdd(&cursor[(size_t)k * CSTRIDE], c) : 0;
    }
    __syncthreads();

    float h  = supp[0];
    float dt = dtp[0];
    float kc = 20.0f * (7.0f / 3.14159265358979323846f) / (h * h * h);

    // phase 2b: compute + cached store (L2 write-combining merges records)
#pragma unroll
    for (int k = 0; k < BIN_EPT; ++k) {
        if (pack[k] < 0) continue;
        int b  = pack[k] >> 22;
        int li = (pack[k] >> 12) & (PB - 1);
        int r  = pack[k] & 4095;
        int slot = lbase[b] + r;
        if (slot >= cap) continue;  // 8-sigma margin; statistically never taken

        float  q = qq[k];
        v2f    d = dd[k];
        float om  = 1.0f - q;
        float mag = kc * q * om * om * om;
        float gx = -d.x * mag;
        float gy = -d.y * mag;
        float g2 = gx * gx + gy * gy;

        float4 a = ja[k];   // {p, r=m/aa, aa, aa^2/m}
        float4 v = jb[k];   // {vx, vy, ax, ay}
        float aa = a.z;
        float c0 = aa * gx;
        float c1 = aa * gy;
        float q5 = dt * (v.x * c0 + v.y * c1);        // dt*aa*(vj.g)
        float q6 = dt * dt * (v.z * c0 + v.w * c1);   // dt^2*aa*(aj.g)

        size_t gs = ((size_t)b * cap + slot) * 2;
        pay[gs]     = make_float4(c0, c1, a.w * g2, a.y);
        pay[gs + 1] = make_float4(a.x, q5, q6, __int_as_float(li));
    }
}

__device__ __forceinline__ void red_edge(
    float4 e0, float4 e1, float sc,
    const float* __restrict__ ip, float* __restrict__ lacc) {
    int li = __float_as_int(e1.w) & (PB - 1);
    float c0 = e0.x * sc;
    float c1 = e0.y * sc;
    float c2 = e0.z * sc;
    float rr = e0.w * sc;
    float pij = ip[li] + e1.x;
    float rc  = -pij * rr;
    float* l = lacc + li * 7;
    atomicAdd(l + 0, c0);           // c0 = aa*gx
    atomicAdd(l + 1, c1);           // c1 = aa*gy
    atomicAdd(l + 2, c2);           // c2
    atomicAdd(l + 3, rc * c0);      // c3 = -(pi+pj)*r*c0  (sc^2 still 0 when masked)
    atomicAdd(l + 4, rc * c1);      // c4
    atomicAdd(l + 5, e1.y * sc);    // q5
    atomicAdd(l + 6, e1.z * sc);    // q6
}

__global__ __launch_bounds__(256) void reduce_kernel(
    const float4* __restrict__ pay,
    const int*    __restrict__ cursor, int cap,
    const float4* __restrict__ pre2,
    const float*  __restrict__ dtp,
    float*        __restrict__ partials,
    int spc, int soff, int n) {
    __shared__ float lacc[PB * 7];   // 14 KB, odd stride
    __shared__ float ip[PB];         //  2 KB
    int b   = blockIdx.x / spc;
    int s   = blockIdx.x % spc;
    int tid = threadIdx.x;
    for (int k = tid; k < PB; k += 256) {
        int p = (b << PB_SHIFT) + k;
        ip[k] = (p < n) ? pre2[2 * (size_t)p].x : 0.f;
    }
    for (int k = tid; k < PB * 7; k += 256) lacc[k] = 0.f;
    __syncthreads();

    int cnt = cursor[(size_t)b * CSTRIDE];
    if (cnt > cap) cnt = cap;
    int lo = (int)((long long)cnt * s / spc);
    int hi = (int)((long long)cnt * (s + 1) / spc);
    size_t base = (size_t)b * cap * 2;

    // batched main loop: all 16 loads issued before any LDS atomic; masked
    // lanes clamp the index and zero-scale their contribution (no serial tail)
    int span  = 256 * RED_EPT;
    int t     = lo + tid;
    for (; t - tid < hi; t += span) {
        float4 e0[RED_EPT], e1[RED_EPT];
        float  sc[RED_EPT];
#pragma unroll
        for (int k = 0; k < RED_EPT; ++k) {
            int tt  = t + k * 256;
            int idx = (tt < hi) ? tt : (hi - 1);
            sc[k]   = (tt < hi) ? 1.f : 0.f;
            e0[k] = pay[base + 2 * (size_t)idx];
            e1[k] = pay[base + 2 * (size_t)idx + 1];
        }
#pragma unroll
        for (int k = 0; k < RED_EPT; ++k)
            red_edge(e0[k], e1[k], sc[k], ip, lacc);
    }
    __syncthreads();

    // epilogue: apply linear i-side corrections, write slice
    float dt  = dtp[0];
    float dt2 = dt * dt;
    float* dst = partials + ((size_t)b * SLICES + soff + s) * (PB * 7);
    for (int k = tid; k < PB; k += 256) {
        int p = (b << PB_SHIFT) + k;
        float4 va = (p < n) ? pre2[2 * (size_t)p + 1]
                            : make_float4(0.f, 0.f, 0.f, 0.f);
        const float* l = &lacc[k * 7];
        float s0 = l[0], s1 = l[1];
        float src = l[5] - dt  * (va.x * s0 + va.y * s1);
        float ker = dt2 * (va.z * s0 + va.w * s1) - l[6];
        float* d = dst + (size_t)k * 7;
        d[0] = s0; d[1] = s1; d[2] = l[2]; d[3] = l[3]; d[4] = l[4];
        d[5] = src; d[6] = ker;
    }
}

// ---- fallback: direct global float atomics ----
__global__ void edge_kernel(const int* __restrict__ nbr,
                            const float* __restrict__ rad,
                            const float2* __restrict__ dirs,
                            const float4* __restrict__ pre2,
                            const float* __restrict__ supp,
                            const float* __restrict__ dtp,
                            float* __restrict__ acc, int E) {
    int e = blockIdx.x * blockDim.x + threadIdx.x;
    if (e >= E) return;
    float h = supp[0], dt = dtp[0];
    float kc = 20.0f * (7.0f / 3.14159265358979323846f) / (h * h * h);
    int i = nbr[e];
    int j = nbr[E + e];
    float  q = rad[e];
    float2 d = dirs[e];
    float om  = 1.0f - q;
    float mag = kc * q * om * om * om;
    float gx = -d.x * mag;
    float gy = -d.y * mag;
    float g2 = gx * gx + gy * gy;
    float4 ja = pre2[2 * (size_t)j];      // {p, r, aa, aa2m}
    float4 jb = pre2[2 * (size_t)j + 1];
    float4 ia = pre2[2 * (size_t)i];
    float4 ib = pre2[2 * (size_t)i + 1];
    float aaj = ja.z;
    float m   = ja.y * aaj;
    float pp  = -m * (ia.x + ja.x);
    float vdotg = (ib.x - jb.x) * gx + (ib.y - jb.y) * gy;
    float adotg = (ib.z - jb.z) * gx + (ib.w - jb.w) * gy;
    float* base = acc + (size_t)i * 8;
    atomicAdd(base + 0, aaj * gx);
    atomicAdd(base + 1, aaj * gy);
    atomicAdd(base + 2, ja.w * g2);
    atomicAdd(base + 3, pp * gx);
    atomicAdd(base + 4, pp * gy);
    atomicAdd(base + 5, -dt * aaj * vdotg);
    atomicAdd(base + 6, dt * dt * aaj * adotg);
}

__global__ __launch_bounds__(256) void fin_kernel(
    const float* __restrict__ area,
    const float* __restrict__ actualArea,
    const float* __restrict__ restDensity,
    const float* __restrict__ dtp,
    const float* __restrict__ data, int mode,
    float* __restrict__ out, int n) {
    int t = blockIdx.x * blockDim.x + threadIdx.x;
    if (t >= n) return;
    float s0 = 0, s1 = 0, s2 = 0, s3 = 0, s4 = 0, s5 = 0, s6 = 0;
    if (mode == 0) {
        const float* base = data + ((size_t)(t >> PB_SHIFT) * SLICES) * (PB * 7)
                                 + (size_t)(t & (PB - 1)) * 7;
#pragma unroll
        for (int s = 0; s < SLICES; ++s) {
            const float* p = base + (size_t)s * (PB * 7);
            s0 += p[0]; s1 += p[1]; s2 += p[2]; s3 += p[3];
            s4 += p[4]; s5 += p[5]; s6 += p[6];
        }
    } else {
        const float* a = data + (size_t)t * 8;
        s0 = a[0]; s1 = a[1]; s2 = a[2]; s3 = a[3];
        s4 = a[4]; s5 = a[5]; s6 = a[6];
    }
    float dt   = dtp[0];
    float fac  = -dt * dt * actualArea[t];
    float mass = area[t] * restDensity[t];
    float alpha = fac / mass * (s0 * s0 + s1 * s1) + fac * s2;
    float* o = out + (size_t)t * 5;
    o[0] = alpha;
    o[1] = s3;
    o[2] = s4;
    o[3] = s5;
    o[4] = s6;
}

extern "C" void kernel_launch(void* const* d_in, const int* in_sizes, int n_in,
                              void* d_out, int out_size, void* d_ws, size_t ws_size,
                              hipStream_t stream) {
    const float* area        = (const float*)d_in[0];
    const float* actualArea  = (const float*)d_in[1];
    const float* restDensity = (const float*)d_in[2];
    const float* density     = (const float*)d_in[3];
    const float* pressure2   = (const float*)d_in[4];
    const float2* vel        = (const float2*)d_in[5];
    const float2* accel      = (const float2*)d_in[6];
    const float* rad         = (const float*)d_in[7];
    const float2* dirs       = (const float2*)d_in[8];
    const int*   nbr         = (const int*)d_in[9];
    const float* supp        = (const float*)d_in[10];
    const float* dtp         = (const float*)d_in[11];
    float* out = (float*)d_out;

    int N = in_sizes[0];
    int E = in_sizes[7];
    int nb = (N + PB - 1) >> PB_SHIFT;   // 512 for N=262144

    size_t sz_cur   = (size_t)nb * CSTRIDE * 4 * sizeof(int);  // up to 4 chunks
    size_t off_pre  = align256(sz_cur);
    size_t sz_pre   = (size_t)N * 8 * sizeof(float);
    size_t off_part = align256(off_pre + sz_pre);
    size_t sz_part  = (size_t)nb * SLICES * PB * 7 * sizeof(float);
    size_t off_pay  = align256(off_part + sz_part);

    int* cursor     = (int*)d_ws;
    float4* pre2    = (float4*)((char*)d_ws + off_pre);
    float* partials = (float*)((char*)d_ws + off_part);

    // pick chunking so payload fits (one 32B record/edge, bucket-grouped)
    int nchunk = 0, cap = 0;
    if (nb <= 512 && ws_size > off_pay) {
        for (int c = 1; c <= SLICES; c *= 2) {
            long long Ec = (E + c - 1) / c;
            double mean = (double)Ec / (double)nb;
            long long need = (long long)(mean + 8.0 * sqrt(mean) + 128.0);
            need = (need + 63) & ~63ll;
            if (off_pay + (size_t)nb * need * 32 <= ws_size) {
                nchunk = c; cap = (int)need; break;
            }
        }
    }

    int bs = 256;
    int grid_n = (N + bs - 1) / bs;
    if (nchunk > 0) {
        float4* pay = (float4*)((char*)d_ws + off_pay);
        int ncursor = nb * CSTRIDE * nchunk;
        pre_kernel<<<grid_n, bs, 0, stream>>>(
            area, actualArea, restDensity, density, pressure2, vel, accel,
            pre2, cursor, ncursor, (float*)nullptr, 0, N);
        int spc = SLICES / nchunk; if (spc < 1) spc = 1;
        int Ec  = (E + nchunk - 1) / nchunk;
        for (int c = 0; c < nchunk; ++c) {
            int es = c * Ec;
            int ee = es + Ec; if (ee > E) ee = E;
            if (es >= ee) break;
            int* curC = cursor + (size_t)c * nb * CSTRIDE;
            int nblk = (ee - es + 256 * BIN_EPT - 1) / (256 * BIN_EPT);
            bin_kernel<<<nblk, bs, 0, stream>>>(
                nbr, rad, dirs, pre2, supp, dtp, curC, pay, cap, nb, es, ee, E);
            reduce_kernel<<<nb * spc, bs, 0, stream>>>(
                pay, curC, cap, pre2, dtp, partials, spc, c * spc, N);
        }
        fin_kernel<<<grid_n, bs, 0, stream>>>(
            area, actualArea, restDensity, dtp, partials, 0, out, N);
    } else {
        float* acc = partials;  // [N,8] at off_part
        pre_kernel<<<grid_n, bs, 0, stream>>>(
            area, actualArea, restDensity, density, pressure2, vel, accel,
            pre2, cursor, 0, acc, N * 8, N);
        edge_kernel<<<(E + bs - 1) / bs, bs, 0, stream>>>(
            nbr, rad, dirs, pre2, supp, dtp, acc, E);
        fin_kernel<<<grid_n, bs, 0, stream>>>(
            area, actualArea, restDensity, dtp, acc, 1, out, N);
    }
}

// Round 10
// 857.359 us; speedup vs baseline: 1.1022x; 1.1022x over previous
//
#include <hip/hip_runtime.h>
#include <math.h>

// -----------------------------------------------------------------------------
// DFSPH divergence-solve, block-aggregated binning, i-side deferred to reduce.
//   pre:    per-particle 32B {p, r=m/aa, aa, aa^2/m | vx,vy,ax,ay}; zero cursors.
//   bin:    2048 edges/block, software-pipelined (round-7 structure):
//             phase 1: stream nbr/rad/dirs (nontemporal) into regs, rank
//                      per-bucket in LDS.
//             phase 2a: issue ALL pre2[j] gathers BEFORE the barrier.
//             claim:   one global cursor atomic per (block,bucket), 1/cacheline.
//             phase 2b: compute, CACHED store of ONE 32B record/edge:
//                      {c0=aa*gx, c1=aa*gy, c2=aa2m*g2, r | pj, q5, q6, li}.
//   reduce: m97-style DMA staging. Per 512-record tile: 4 waves issue 16
//           global_load_lds_dwordx4 each (payload -> 16KB LDS stage, zero data
//           VGPRs, deep MLP via the DMA queue), __syncthreads (drains vmcnt),
//           each thread processes 2 records from LDS (7 LDS atomics each,
//           sc-masked tail -> no divergence), sync, next tile. Rounds 8/9
//           proved the compiler won't hold register MLP across LDS atomics
//           (VGPR stuck at 24-40); the DMA engine sidesteps that entirely.
//           i-side v/a corrections are linear -> applied once per particle at
//           slice-write. No global float atomics.
//   fin:    sum SLICES=8 slices, alpha, write [N,5].
// Fallback (tiny ws): direct global float atomics.
// -----------------------------------------------------------------------------

#define PB        512
#define PB_SHIFT  9
#define SLICES    8
#define CSTRIDE   16      // ints per cursor -> 64B, one cacheline each
#define BIN_EPT   8       // edges per thread in bin
#define TILE      512     // records staged per reduce tile (16 KB LDS)

typedef float v2f __attribute__((ext_vector_type(2)));

__device__ __forceinline__ void gload_lds16(const float4* g, float4* l) {
    __builtin_amdgcn_global_load_lds(
        (const __attribute__((address_space(1))) void*)g,
        (__attribute__((address_space(3))) void*)l, 16, 0, 0);
}

static inline size_t align256(size_t x) { return (x + 255) & ~(size_t)255; }

__global__ __launch_bounds__(256) void pre_kernel(
    const float*  __restrict__ area,
    const float*  __restrict__ actualArea,
    const float*  __restrict__ restDensity,
    const float*  __restrict__ density,
    const float*  __restrict__ pressure2,
    const float2* __restrict__ vel,
    const float2* __restrict__ accel,
    float4* __restrict__ pre2,
    int*    __restrict__ cursor, int ncursor,
    float*  __restrict__ accz, int nacc,
    int n) {
    int t = blockIdx.x * blockDim.x + threadIdx.x;
    if (t < ncursor) cursor[t] = 0;
    for (int k = t; k < nacc; k += gridDim.x * blockDim.x) accz[k] = 0.f;
    if (t >= n) return;
    float m  = area[t] * restDensity[t];
    float dr = density[t] * restDensity[t];
    float p  = pressure2[t] / (dr * dr);
    float aa = actualArea[t];
    float2 v  = vel[t];
    float2 ac = accel[t];
    pre2[2 * (size_t)t]     = make_float4(p, m / aa, aa, aa * aa / m);
    pre2[2 * (size_t)t + 1] = make_float4(v.x, v.y, ac.x, ac.y);
}

__global__ __launch_bounds__(256) void bin_kernel(
    const int*    __restrict__ nbr,
    const float*  __restrict__ rad,
    const float2* __restrict__ dirs,
    const float4* __restrict__ pre2,
    const float*  __restrict__ supp,
    const float*  __restrict__ dtp,
    int*          __restrict__ cursor,
    float4*       __restrict__ pay,
    int cap, int nb, int estart, int eend, int E) {
    __shared__ int lcount[512];
    __shared__ int lbase[512];
    int tid = threadIdx.x;
    for (int k = tid; k < nb; k += 256) lcount[k] = 0;
    __syncthreads();
    int e0 = estart + blockIdx.x * (256 * BIN_EPT) + tid;

    // phase 1: stream everything per-edge into registers, rank per bucket
    int jj[BIN_EPT]; float qq[BIN_EPT]; v2f dd[BIN_EPT]; int pack[BIN_EPT];
#pragma unroll
    for (int k = 0; k < BIN_EPT; ++k) {
        int e = e0 + k * 256;
        pack[k] = -1; jj[k] = 0; qq[k] = 0.f; dd[k] = (v2f){0.f, 0.f};
        if (e < eend) {
            jj[k] = __builtin_nontemporal_load(nbr + E + e);
            qq[k] = __builtin_nontemporal_load(rad + e);
            dd[k] = __builtin_nontemporal_load((const v2f*)dirs + e);
            int i = __builtin_nontemporal_load(nbr + e);
            int b = i >> PB_SHIFT;
            int r = atomicAdd(&lcount[b], 1);
            pack[k] = (b << 22) | ((i & (PB - 1)) << 12) | r;
        }
    }

    // phase 2a: issue ALL gathers before the barrier
    float4 ja[BIN_EPT], jb[BIN_EPT];
#pragma unroll
    for (int k = 0; k < BIN_EPT; ++k) {
        size_t j2 = 2 * (size_t)jj[k];
        ja[k] = pre2[j2];
        jb[k] = pre2[j2 + 1];
    }

    __syncthreads();
    // one global cursor claim per (block,bucket)
    for (int k = tid; k < nb; k += 256) {
        int c = lcount[k];
        lbase[k] = c ? atomicAdd(&cursor[(size_t)k * CSTRIDE], c) : 0;
    }
    __syncthreads();

    float h  = supp[0];
    float dt = dtp[0];
    float kc = 20.0f * (7.0f / 3.14159265358979323846f) / (h * h * h);

    // phase 2b: compute + cached store (L2 merges adjacent records per line)
#pragma unroll
    for (int k = 0; k < BIN_EPT; ++k) {
        if (pack[k] < 0) continue;
        int b  = pack[k] >> 22;
        int li = (pack[k] >> 12) & (PB - 1);
        int r  = pack[k] & 4095;
        int slot = lbase[b] + r;
        if (slot >= cap) continue;  // 8-sigma margin; statistically never taken

        float  q = qq[k];
        v2f    d = dd[k];
        float om  = 1.0f - q;
        float mag = kc * q * om * om * om;
        float gx = -d.x * mag;
        float gy = -d.y * mag;
        float g2 = gx * gx + gy * gy;

        float4 a = ja[k];   // {p, r=m/aa, aa, aa^2/m}
        float4 v = jb[k];   // {vx, vy, ax, ay}
        float aa = a.z;
        float c0 = aa * gx;
        float c1 = aa * gy;
        float q5 = dt * (v.x * c0 + v.y * c1);        // dt*aa*(vj.g)
        float q6 = dt * dt * (v.z * c0 + v.w * c1);   // dt^2*aa*(aj.g)

        size_t gs = ((size_t)b * cap + slot) * 2;
        pay[gs]     = make_float4(c0, c1, a.w * g2, a.y);
        pay[gs + 1] = make_float4(a.x, q5, q6, __int_as_float(li));
    }
}

__device__ __forceinline__ void red_edge(
    float4 e0, float4 e1, float sc,
    const float* __restrict__ ip, float* __restrict__ lacc) {
    int li = __float_as_int(e1.w) & (PB - 1);
    float c0 = e0.x * sc;
    float c1 = e0.y * sc;
    float c2 = e0.z * sc;
    float rr = e0.w * sc;
    float pij = ip[li] + e1.x;
    float rc  = -pij * rr;
    float* l = lacc + li * 7;
    atomicAdd(l + 0, c0);           // c0 = aa*gx
    atomicAdd(l + 1, c1);           // c1 = aa*gy
    atomicAdd(l + 2, c2);           // c2
    atomicAdd(l + 3, rc * c0);      // c3 = -(pi+pj)*r*c0
    atomicAdd(l + 4, rc * c1);      // c4
    atomicAdd(l + 5, e1.y * sc);    // q5
    atomicAdd(l + 6, e1.z * sc);    // q6
}

__global__ __launch_bounds__(256) void reduce_kernel(
    const float4* __restrict__ pay,
    const int*    __restrict__ cursor, int cap,
    const float4* __restrict__ pre2,
    const float*  __restrict__ dtp,
    float*        __restrict__ partials,
    int spc, int soff, int n) {
    __shared__ float  lacc[PB * 7];    // 14 KB
    __shared__ float  ip[PB];          //  2 KB
    __shared__ float4 stage[TILE * 2]; // 16 KB staging tile (512 records)
    int b   = blockIdx.x / spc;
    int s   = blockIdx.x % spc;
    int tid = threadIdx.x;
    int w    = tid >> 6;
    int lane = tid & 63;
    for (int k = tid; k < PB; k += 256) {
        int p = (b << PB_SHIFT) + k;
        ip[k] = (p < n) ? pre2[2 * (size_t)p].x : 0.f;
    }
    for (int k = tid; k < PB * 7; k += 256) lacc[k] = 0.f;
    __syncthreads();

    int cnt = cursor[(size_t)b * CSTRIDE];
    if (cnt > cap) cnt = cap;
    int lo = (int)((long long)cnt * s / spc);
    int hi = (int)((long long)cnt * (s + 1) / spc);
    size_t base2 = (size_t)b * cap * 2;

    for (int T = lo; T < hi; T += TILE) {
        // stage 512 records (1024 float4) via DMA: wave w covers f4 indices
        // [w*256, w*256+256), 4 instructions of 64 lanes x 16B each.
#pragma unroll
        for (int si = 0; si < 4; ++si) {
            int fl  = (w << 8) + (si << 6) + lane;    // 0..1023
            int rec = T + (fl >> 1);
            size_t g = (rec < hi) ? (base2 + 2 * (size_t)rec + (fl & 1)) : base2;
            gload_lds16(pay + g, stage + fl);
        }
        __syncthreads();   // drains vmcnt -> staged data visible
        // process 2 records per thread from LDS (tail is sc-masked, no branch)
#pragma unroll
        for (int k = 0; k < 2; ++k) {
            int rl  = tid + (k << 8);
            float sc = (T + rl < hi) ? 1.f : 0.f;
            float4 e0 = stage[2 * rl];
            float4 e1 = stage[2 * rl + 1];
            red_edge(e0, e1, sc, ip, lacc);
        }
        __syncthreads();   // protect stage before next tile's DMA
    }
    __syncthreads();

    // epilogue: apply linear i-side corrections, write slice
    float dt  = dtp[0];
    float dt2 = dt * dt;
    float* dst = partials + ((size_t)b * SLICES + soff + s) * (PB * 7);
    for (int k = tid; k < PB; k += 256) {
        int p = (b << PB_SHIFT) + k;
        float4 va = (p < n) ? pre2[2 * (size_t)p + 1]
                            : make_float4(0.f, 0.f, 0.f, 0.f);
        const float* l = &lacc[k * 7];
        float s0 = l[0], s1 = l[1];
        float src = l[5] - dt  * (va.x * s0 + va.y * s1);
        float ker = dt2 * (va.z * s0 + va.w * s1) - l[6];
        float* d = dst + (size_t)k * 7;
        d[0] = s0; d[1] = s1; d[2] = l[2]; d[3] = l[3]; d[4] = l[4];
        d[5] = src; d[6] = ker;
    }
}

// ---- fallback: direct global float atomics ----
__global__ void edge_kernel(const int* __restrict__ nbr,
                            const float* __restrict__ rad,
                            const float2* __restrict__ dirs,
                            const float4* __restrict__ pre2,
                            const float* __restrict__ supp,
                            const float* __restrict__ dtp,
                            float* __restrict__ acc, int E) {
    int e = blockIdx.x * blockDim.x + threadIdx.x;
    if (e >= E) return;
    float h = supp[0], dt = dtp[0];
    float kc = 20.0f * (7.0f / 3.14159265358979323846f) / (h * h * h);
    int i = nbr[e];
    int j = nbr[E + e];
    float  q = rad[e];
    float2 d = dirs[e];
    float om  = 1.0f - q;
    float mag = kc * q * om * om * om;
    float gx = -d.x * mag;
    float gy = -d.y * mag;
    float g2 = gx * gx + gy * gy;
    float4 ja = pre2[2 * (size_t)j];      // {p, r, aa, aa2m}
    float4 jb = pre2[2 * (size_t)j + 1];
    float4 ia = pre2[2 * (size_t)i];
    float4 ib = pre2[2 * (size_t)i + 1];
    float aaj = ja.z;
    float m   = ja.y * aaj;
    float pp  = -m * (ia.x + ja.x);
    float vdotg = (ib.x - jb.x) * gx + (ib.y - jb.y) * gy;
    float adotg = (ib.z - jb.z) * gx + (ib.w - jb.w) * gy;
    float* base = acc + (size_t)i * 8;
    atomicAdd(base + 0, aaj * gx);
    atomicAdd(base + 1, aaj * gy);
    atomicAdd(base + 2, ja.w * g2);
    atomicAdd(base + 3, pp * gx);
    atomicAdd(base + 4, pp * gy);
    atomicAdd(base + 5, -dt * aaj * vdotg);
    atomicAdd(base + 6, dt * dt * aaj * adotg);
}

__global__ __launch_bounds__(256) void fin_kernel(
    const float* __restrict__ area,
    const float* __restrict__ actualArea,
    const float* __restrict__ restDensity,
    const float* __restrict__ dtp,
    const float* __restrict__ data, int mode,
    float* __restrict__ out, int n) {
    int t = blockIdx.x * blockDim.x + threadIdx.x;
    if (t >= n) return;
    float s0 = 0, s1 = 0, s2 = 0, s3 = 0, s4 = 0, s5 = 0, s6 = 0;
    if (mode == 0) {
        const float* base = data + ((size_t)(t >> PB_SHIFT) * SLICES) * (PB * 7)
                                 + (size_t)(t & (PB - 1)) * 7;
#pragma unroll
        for (int s = 0; s < SLICES; ++s) {
            const float* p = base + (size_t)s * (PB * 7);
            s0 += p[0]; s1 += p[1]; s2 += p[2]; s3 += p[3];
            s4 += p[4]; s5 += p[5]; s6 += p[6];
        }
    } else {
        const float* a = data + (size_t)t * 8;
        s0 = a[0]; s1 = a[1]; s2 = a[2]; s3 = a[3];
        s4 = a[4]; s5 = a[5]; s6 = a[6];
    }
    float dt   = dtp[0];
    float fac  = -dt * dt * actualArea[t];
    float mass = area[t] * restDensity[t];
    float alpha = fac / mass * (s0 * s0 + s1 * s1) + fac * s2;
    float* o = out + (size_t)t * 5;
    o[0] = alpha;
    o[1] = s3;
    o[2] = s4;
    o[3] = s5;
    o[4] = s6;
}

extern "C" void kernel_launch(void* const* d_in, const int* in_sizes, int n_in,
                              void* d_out, int out_size, void* d_ws, size_t ws_size,
                              hipStream_t stream) {
    const float* area        = (const float*)d_in[0];
    const float* actualArea  = (const float*)d_in[1];
    const float* restDensity = (const float*)d_in[2];
    const float* density     = (const float*)d_in[3];
    const float* pressure2   = (const float*)d_in[4];
    const float2* vel        = (const float2*)d_in[5];
    const float2* accel      = (const float2*)d_in[6];
    const float* rad         = (const float*)d_in[7];
    const float2* dirs       = (const float2*)d_in[8];
    const int*   nbr         = (const int*)d_in[9];
    const float* supp        = (const float*)d_in[10];
    const float* dtp         = (const float*)d_in[11];
    float* out = (float*)d_out;

    int N = in_sizes[0];
    int E = in_sizes[7];
    int nb = (N + PB - 1) >> PB_SHIFT;   // 512 for N=262144

    size_t sz_cur   = (size_t)nb * CSTRIDE * 8 * sizeof(int);
    size_t off_pre  = align256(sz_cur);
    size_t sz_pre   = (size_t)N * 8 * sizeof(float);
    size_t off_part = align256(off_pre + sz_pre);
    size_t sz_part  = (size_t)nb * SLICES * PB * 7 * sizeof(float);
    size_t off_pay  = align256(off_part + sz_part);

    int* cursor     = (int*)d_ws;
    float4* pre2    = (float4*)((char*)d_ws + off_pre);
    float* partials = (float*)((char*)d_ws + off_part);

    // pick chunking so payload fits (one 32B record/edge, bucket-grouped)
    int nchunk = 0, cap = 0;
    if (nb <= 512 && ws_size > off_pay) {
        for (int c = 1; c <= 8; c *= 2) {
            long long Ec = (E + c - 1) / c;
            double mean = (double)Ec / (double)nb;
            long long need = (long long)(mean + 8.0 * sqrt(mean) + 128.0);
            need = (need + 63) & ~63ll;
            if (off_pay + (size_t)nb * need * 32 <= ws_size) {
                nchunk = c; cap = (int)need; break;
            }
        }
    }

    int bs = 256;
    int grid_n = (N + bs - 1) / bs;
    if (nchunk > 0) {
        float4* pay = (float4*)((char*)d_ws + off_pay);
        int ncursor = nb * CSTRIDE * nchunk;
        pre_kernel<<<grid_n, bs, 0, stream>>>(
            area, actualArea, restDensity, density, pressure2, vel, accel,
            pre2, cursor, ncursor, (float*)nullptr, 0, N);
        int spc = SLICES / nchunk; if (spc < 1) spc = 1;
        int Ec  = (E + nchunk - 1) / nchunk;
        for (int c = 0; c < nchunk; ++c) {
            int es = c * Ec;
            int ee = es + Ec; if (ee > E) ee = E;
            if (es >= ee) break;
            int* curC = cursor + (size_t)c * nb * CSTRIDE;
            int nblk = (ee - es + 256 * BIN_EPT - 1) / (256 * BIN_EPT);
            bin_kernel<<<nblk, bs, 0, stream>>>(
                nbr, rad, dirs, pre2, supp, dtp, curC, pay, cap, nb, es, ee, E);
            reduce_kernel<<<nb * spc, bs, 0, stream>>>(
                pay, curC, cap, pre2, dtp, partials, spc, c * spc, N);
        }
        fin_kernel<<<grid_n, bs, 0, stream>>>(
            area, actualArea, restDensity, dtp, partials, 0, out, N);
    } else {
        float* acc = partials;  // [N,8] at off_part
        pre_kernel<<<grid_n, bs, 0, stream>>>(
            area, actualArea, restDensity, density, pressure2, vel, accel,
            pre2, cursor, 0, acc, N * 8, N);
        edge_kernel<<<(E + bs - 1) / bs, bs, 0, stream>>>(
            nbr, rad, dirs, pre2, supp, dtp, acc, E);
        fin_kernel<<<grid_n, bs, 0, stream>>>(
            area, actualArea, restDensity, dtp, acc, 1, out, N);
    }
}

// Round 11
// 564.472 us; speedup vs baseline: 1.6741x; 1.5189x over previous
//
#include <hip/hip_runtime.h>
#include <math.h>

// -----------------------------------------------------------------------------
// DFSPH divergence-solve, block-aggregated binning + sort-based reduce.
//   pre:    per-particle 32B {p, r=m/aa, aa, aa^2/m | vx,vy,ax,ay}; zero cursors.
//   bin:    2048 edges/block (round-7 structure, stable ~160us/chunk):
//           rank per-bucket in LDS, pre-barrier pre2[j] gathers, one cursor
//           atomic per (block,bucket), ONE cached 32B record/edge:
//           {c0=aa*gx, c1=aa*gy, c2=aa2m*g2, r | pj, q5, q6, li}.
//   reduce: rounds 3-10 showed ~155-215us/chunk REGARDLESS of memory strategy
//           -> floor = 7 LDS atomicAdds/record (29.4M lane-RMWs/chunk on the DS
//           pipe). This version does an in-LDS counting sort per 512-record
//           tile (1 int atomic/record) then each thread serially accumulates
//           its 2 particles' contiguous segments into REGISTERS (no atomics):
//             DMA stage -> sync -> hist -> sync -> wave0 exclusive scan ->
//             sync -> scatter to sorted order -> sync -> register gather.
//           i-side v/a corrections are linear -> applied once per particle at
//           slice-write. No global float atomics anywhere.
//   fin:    sum SLICES=8 slices, alpha, write [N,5].
// Fallback (tiny ws): direct global float atomics.
// -----------------------------------------------------------------------------

#define PB        512
#define PB_SHIFT  9
#define SLICES    8
#define CSTRIDE   16      // ints per cursor -> 64B, one cacheline each
#define BIN_EPT   8       // edges per thread in bin
#define TILE      512     // records staged per reduce tile (16 KB LDS)

typedef float v2f __attribute__((ext_vector_type(2)));

__device__ __forceinline__ void gload_lds16(const float4* g, float4* l) {
    __builtin_amdgcn_global_load_lds(
        (const __attribute__((address_space(1))) void*)g,
        (__attribute__((address_space(3))) void*)l, 16, 0, 0);
}

static inline size_t align256(size_t x) { return (x + 255) & ~(size_t)255; }

__global__ __launch_bounds__(256) void pre_kernel(
    const float*  __restrict__ area,
    const float*  __restrict__ actualArea,
    const float*  __restrict__ restDensity,
    const float*  __restrict__ density,
    const float*  __restrict__ pressure2,
    const float2* __restrict__ vel,
    const float2* __restrict__ accel,
    float4* __restrict__ pre2,
    int*    __restrict__ cursor, int ncursor,
    float*  __restrict__ accz, int nacc,
    int n) {
    int t = blockIdx.x * blockDim.x + threadIdx.x;
    if (t < ncursor) cursor[t] = 0;
    for (int k = t; k < nacc; k += gridDim.x * blockDim.x) accz[k] = 0.f;
    if (t >= n) return;
    float m  = area[t] * restDensity[t];
    float dr = density[t] * restDensity[t];
    float p  = pressure2[t] / (dr * dr);
    float aa = actualArea[t];
    float2 v  = vel[t];
    float2 ac = accel[t];
    pre2[2 * (size_t)t]     = make_float4(p, m / aa, aa, aa * aa / m);
    pre2[2 * (size_t)t + 1] = make_float4(v.x, v.y, ac.x, ac.y);
}

__global__ __launch_bounds__(256) void bin_kernel(
    const int*    __restrict__ nbr,
    const float*  __restrict__ rad,
    const float2* __restrict__ dirs,
    const float4* __restrict__ pre2,
    const float*  __restrict__ supp,
    const float*  __restrict__ dtp,
    int*          __restrict__ cursor,
    float4*       __restrict__ pay,
    int cap, int nb, int estart, int eend, int E) {
    __shared__ int lcount[512];
    __shared__ int lbase[512];
    int tid = threadIdx.x;
    for (int k = tid; k < nb; k += 256) lcount[k] = 0;
    __syncthreads();
    int e0 = estart + blockIdx.x * (256 * BIN_EPT) + tid;

    // phase 1: stream everything per-edge into registers, rank per bucket
    int jj[BIN_EPT]; float qq[BIN_EPT]; v2f dd[BIN_EPT]; int pack[BIN_EPT];
#pragma unroll
    for (int k = 0; k < BIN_EPT; ++k) {
        int e = e0 + k * 256;
        pack[k] = -1; jj[k] = 0; qq[k] = 0.f; dd[k] = (v2f){0.f, 0.f};
        if (e < eend) {
            jj[k] = __builtin_nontemporal_load(nbr + E + e);
            qq[k] = __builtin_nontemporal_load(rad + e);
            dd[k] = __builtin_nontemporal_load((const v2f*)dirs + e);
            int i = __builtin_nontemporal_load(nbr + e);
            int b = i >> PB_SHIFT;
            int r = atomicAdd(&lcount[b], 1);
            pack[k] = (b << 22) | ((i & (PB - 1)) << 12) | r;
        }
    }

    // phase 2a: issue ALL gathers before the barrier
    float4 ja[BIN_EPT], jb[BIN_EPT];
#pragma unroll
    for (int k = 0; k < BIN_EPT; ++k) {
        size_t j2 = 2 * (size_t)jj[k];
        ja[k] = pre2[j2];
        jb[k] = pre2[j2 + 1];
    }

    __syncthreads();
    // one global cursor claim per (block,bucket)
    for (int k = tid; k < nb; k += 256) {
        int c = lcount[k];
        lbase[k] = c ? atomicAdd(&cursor[(size_t)k * CSTRIDE], c) : 0;
    }
    __syncthreads();

    float h  = supp[0];
    float dt = dtp[0];
    float kc = 20.0f * (7.0f / 3.14159265358979323846f) / (h * h * h);

    // phase 2b: compute + cached store (L2 merges adjacent records per line)
#pragma unroll
    for (int k = 0; k < BIN_EPT; ++k) {
        if (pack[k] < 0) continue;
        int b  = pack[k] >> 22;
        int li = (pack[k] >> 12) & (PB - 1);
        int r  = pack[k] & 4095;
        int slot = lbase[b] + r;
        if (slot >= cap) continue;  // 8-sigma margin; statistically never taken

        float  q = qq[k];
        v2f    d = dd[k];
        float om  = 1.0f - q;
        float mag = kc * q * om * om * om;
        float gx = -d.x * mag;
        float gy = -d.y * mag;
        float g2 = gx * gx + gy * gy;

        float4 a = ja[k];   // {p, r=m/aa, aa, aa^2/m}
        float4 v = jb[k];   // {vx, vy, ax, ay}
        float aa = a.z;
        float c0 = aa * gx;
        float c1 = aa * gy;
        float q5 = dt * (v.x * c0 + v.y * c1);        // dt*aa*(vj.g)
        float q6 = dt * dt * (v.z * c0 + v.w * c1);   // dt^2*aa*(aj.g)

        size_t gs = ((size_t)b * cap + slot) * 2;
        pay[gs]     = make_float4(c0, c1, a.w * g2, a.y);
        pay[gs + 1] = make_float4(a.x, q5, q6, __int_as_float(li));
    }
}

__global__ __launch_bounds__(256) void reduce_kernel(
    const float4* __restrict__ pay,
    const int*    __restrict__ cursor, int cap,
    const float4* __restrict__ pre2,
    const float*  __restrict__ dtp,
    float*        __restrict__ partials,
    int spc, int soff, int n) {
    __shared__ float4 stage[TILE * 2];   // 16 KB raw staged tile
    __shared__ float4 sorted[TILE * 2];  // 16 KB particle-sorted tile
    __shared__ int    lhist[PB];         //  2 KB counts
    __shared__ int    lofs[PB];          //  2 KB exclusive offsets -> cursors
    int b   = blockIdx.x / spc;
    int s   = blockIdx.x % spc;
    int tid = threadIdx.x;
    int w    = tid >> 6;
    int lane = tid & 63;

    // this thread owns particles p0 = base+tid and p1 = base+tid+256
    int p0 = (b << PB_SHIFT) + tid;
    int p1 = p0 + 256;
    float pi0 = (p0 < n) ? pre2[2 * (size_t)p0].x : 0.f;
    float pi1 = (p1 < n) ? pre2[2 * (size_t)p1].x : 0.f;
    float a0[7] = {0.f, 0.f, 0.f, 0.f, 0.f, 0.f, 0.f};
    float a1[7] = {0.f, 0.f, 0.f, 0.f, 0.f, 0.f, 0.f};

    int cnt = cursor[(size_t)b * CSTRIDE];
    if (cnt > cap) cnt = cap;
    int lo = (int)((long long)cnt * s / spc);
    int hi = (int)((long long)cnt * (s + 1) / spc);
    size_t base2 = (size_t)b * cap * 2;

    for (int T = lo; T < hi; T += TILE) {
        // stage 512 records (1024 float4) via DMA (stage is free: last reader
        // was the previous tile's scatter, which completed before its gather)
#pragma unroll
        for (int si = 0; si < 4; ++si) {
            int fl  = (w << 8) + (si << 6) + lane;    // 0..1023
            int rec = T + (fl >> 1);
            size_t g = (rec < hi) ? (base2 + 2 * (size_t)rec + (fl & 1)) : base2;
            gload_lds16(pay + g, stage + fl);
        }
        __syncthreads();      // prev gather done (lhist/lofs/sorted free) + DMA drained
        lhist[tid] = 0; lhist[tid + 256] = 0;
        __syncthreads();
        // histogram by local particle id (1 atomic per record)
#pragma unroll
        for (int k = 0; k < 2; ++k) {
            int rl = tid + (k << 8);
            if (T + rl < hi) {
                int li = __float_as_int(stage[2 * rl + 1].w) & (PB - 1);
                atomicAdd(&lhist[li], 1);
            }
        }
        __syncthreads();
        // exclusive prefix scan of 512 counts by wave 0
        if (tid < 64) {
            int running = 0;
            for (int c = 0; c < 8; ++c) {
                int orig = lhist[c * 64 + tid];
                int v = orig;
#pragma unroll
                for (int off = 1; off < 64; off <<= 1) {
                    int u = __shfl_up(v, off, 64);
                    if (tid >= off) v += u;
                }
                lofs[c * 64 + tid] = running + v - orig;
                running += __shfl(v, 63, 64);
            }
        }
        __syncthreads();
        // scatter into particle-sorted order (lofs becomes per-particle cursor)
#pragma unroll
        for (int k = 0; k < 2; ++k) {
            int rl = tid + (k << 8);
            if (T + rl < hi) {
                float4 e0 = stage[2 * rl];
                float4 e1 = stage[2 * rl + 1];
                int li = __float_as_int(e1.w) & (PB - 1);
                int slot = atomicAdd(&lofs[li], 1);
                sorted[2 * slot]     = e0;
                sorted[2 * slot + 1] = e1;
            }
        }
        __syncthreads();
        // register gather: contiguous segment per particle, NO atomics
        {
            int end0 = lofs[tid];
            for (int r = end0 - lhist[tid]; r < end0; ++r) {
                float4 e0 = sorted[2 * r];
                float4 e1 = sorted[2 * r + 1];
                float rc = -(pi0 + e1.x) * e0.w;
                a0[0] += e0.x; a0[1] += e0.y; a0[2] += e0.z;
                a0[3] += rc * e0.x; a0[4] += rc * e0.y;
                a0[5] += e1.y; a0[6] += e1.z;
            }
            int end1 = lofs[tid + 256];
            for (int r = end1 - lhist[tid + 256]; r < end1; ++r) {
                float4 e0 = sorted[2 * r];
                float4 e1 = sorted[2 * r + 1];
                float rc = -(pi1 + e1.x) * e0.w;
                a1[0] += e0.x; a1[1] += e0.y; a1[2] += e0.z;
                a1[3] += rc * e0.x; a1[4] += rc * e0.y;
                a1[5] += e1.y; a1[6] += e1.z;
            }
        }
        // loop-top sync protects stage/lhist/lofs/sorted
    }

    // epilogue: apply linear i-side corrections, write slice from registers
    float dt  = dtp[0];
    float dt2 = dt * dt;
    float* dst = partials + ((size_t)b * SLICES + soff + s) * (PB * 7);
    {
        float4 va = (p0 < n) ? pre2[2 * (size_t)p0 + 1]
                             : make_float4(0.f, 0.f, 0.f, 0.f);
        float src = a0[5] - dt  * (va.x * a0[0] + va.y * a0[1]);
        float ker = dt2 * (va.z * a0[0] + va.w * a0[1]) - a0[6];
        float* d = dst + (size_t)tid * 7;
        d[0] = a0[0]; d[1] = a0[1]; d[2] = a0[2]; d[3] = a0[3]; d[4] = a0[4];
        d[5] = src;   d[6] = ker;
    }
    {
        float4 va = (p1 < n) ? pre2[2 * (size_t)p1 + 1]
                             : make_float4(0.f, 0.f, 0.f, 0.f);
        float src = a1[5] - dt  * (va.x * a1[0] + va.y * a1[1]);
        float ker = dt2 * (va.z * a1[0] + va.w * a1[1]) - a1[6];
        float* d = dst + (size_t)(tid + 256) * 7;
        d[0] = a1[0]; d[1] = a1[1]; d[2] = a1[2]; d[3] = a1[3]; d[4] = a1[4];
        d[5] = src;   d[6] = ker;
    }
}

// ---- fallback: direct global float atomics ----
__global__ void edge_kernel(const int* __restrict__ nbr,
                            const float* __restrict__ rad,
                            const float2* __restrict__ dirs,
                            const float4* __restrict__ pre2,
                            const float* __restrict__ supp,
                            const float* __restrict__ dtp,
                            float* __restrict__ acc, int E) {
    int e = blockIdx.x * blockDim.x + threadIdx.x;
    if (e >= E) return;
    float h = supp[0], dt = dtp[0];
    float kc = 20.0f * (7.0f / 3.14159265358979323846f) / (h * h * h);
    int i = nbr[e];
    int j = nbr[E + e];
    float  q = rad[e];
    float2 d = dirs[e];
    float om  = 1.0f - q;
    float mag = kc * q * om * om * om;
    float gx = -d.x * mag;
    float gy = -d.y * mag;
    float g2 = gx * gx + gy * gy;
    float4 ja = pre2[2 * (size_t)j];      // {p, r, aa, aa2m}
    float4 jb = pre2[2 * (size_t)j + 1];
    float4 ia = pre2[2 * (size_t)i];
    float4 ib = pre2[2 * (size_t)i + 1];
    float aaj = ja.z;
    float m   = ja.y * aaj;
    float pp  = -m * (ia.x + ja.x);
    float vdotg = (ib.x - jb.x) * gx + (ib.y - jb.y) * gy;
    float adotg = (ib.z - jb.z) * gx + (ib.w - jb.w) * gy;
    float* base = acc + (size_t)i * 8;
    atomicAdd(base + 0, aaj * gx);
    atomicAdd(base + 1, aaj * gy);
    atomicAdd(base + 2, ja.w * g2);
    atomicAdd(base + 3, pp * gx);
    atomicAdd(base + 4, pp * gy);
    atomicAdd(base + 5, -dt * aaj * vdotg);
    atomicAdd(base + 6, dt * dt * aaj * adotg);
}

__global__ __launch_bounds__(256) void fin_kernel(
    const float* __restrict__ area,
    const float* __restrict__ actualArea,
    const float* __restrict__ restDensity,
    const float* __restrict__ dtp,
    const float* __restrict__ data, int mode,
    float* __restrict__ out, int n) {
    int t = blockIdx.x * blockDim.x + threadIdx.x;
    if (t >= n) return;
    float s0 = 0, s1 = 0, s2 = 0, s3 = 0, s4 = 0, s5 = 0, s6 = 0;
    if (mode == 0) {
        const float* base = data + ((size_t)(t >> PB_SHIFT) * SLICES) * (PB * 7)
                                 + (size_t)(t & (PB - 1)) * 7;
#pragma unroll
        for (int s = 0; s < SLICES; ++s) {
            const float* p = base + (size_t)s * (PB * 7);
            s0 += p[0]; s1 += p[1]; s2 += p[2]; s3 += p[3];
            s4 += p[4]; s5 += p[5]; s6 += p[6];
        }
    } else {
        const float* a = data + (size_t)t * 8;
        s0 = a[0]; s1 = a[1]; s2 = a[2]; s3 = a[3];
        s4 = a[4]; s5 = a[5]; s6 = a[6];
    }
    float dt   = dtp[0];
    float fac  = -dt * dt * actualArea[t];
    float mass = area[t] * restDensity[t];
    float alpha = fac / mass * (s0 * s0 + s1 * s1) + fac * s2;
    float* o = out + (size_t)t * 5;
    o[0] = alpha;
    o[1] = s3;
    o[2] = s4;
    o[3] = s5;
    o[4] = s6;
}

extern "C" void kernel_launch(void* const* d_in, const int* in_sizes, int n_in,
                              void* d_out, int out_size, void* d_ws, size_t ws_size,
                              hipStream_t stream) {
    const float* area        = (const float*)d_in[0];
    const float* actualArea  = (const float*)d_in[1];
    const float* restDensity = (const float*)d_in[2];
    const float* density     = (const float*)d_in[3];
    const float* pressure2   = (const float*)d_in[4];
    const float2* vel        = (const float2*)d_in[5];
    const float2* accel      = (const float2*)d_in[6];
    const float* rad         = (const float*)d_in[7];
    const float2* dirs       = (const float2*)d_in[8];
    const int*   nbr         = (const int*)d_in[9];
    const float* supp        = (const float*)d_in[10];
    const float* dtp         = (const float*)d_in[11];
    float* out = (float*)d_out;

    int N = in_sizes[0];
    int E = in_sizes[7];
    int nb = (N + PB - 1) >> PB_SHIFT;   // 512 for N=262144

    size_t sz_cur   = (size_t)nb * CSTRIDE * 8 * sizeof(int);
    size_t off_pre  = align256(sz_cur);
    size_t sz_pre   = (size_t)N * 8 * sizeof(float);
    size_t off_part = align256(off_pre + sz_pre);
    size_t sz_part  = (size_t)nb * SLICES * PB * 7 * sizeof(float);
    size_t off_pay  = align256(off_part + sz_part);

    int* cursor     = (int*)d_ws;
    float4* pre2    = (float4*)((char*)d_ws + off_pre);
    float* partials = (float*)((char*)d_ws + off_part);

    // pick chunking so payload fits (one 32B record/edge, bucket-grouped)
    int nchunk = 0, cap = 0;
    if (nb <= 512 && ws_size > off_pay) {
        for (int c = 1; c <= 8; c *= 2) {
            long long Ec = (E + c - 1) / c;
            double mean = (double)Ec / (double)nb;
            long long need = (long long)(mean + 8.0 * sqrt(mean) + 128.0);
            need = (need + 63) & ~63ll;
            if (off_pay + (size_t)nb * need * 32 <= ws_size) {
                nchunk = c; cap = (int)need; break;
            }
        }
    }

    int bs = 256;
    int grid_n = (N + bs - 1) / bs;
    if (nchunk > 0) {
        float4* pay = (float4*)((char*)d_ws + off_pay);
        int ncursor = nb * CSTRIDE * nchunk;
        pre_kernel<<<grid_n, bs, 0, stream>>>(
            area, actualArea, restDensity, density, pressure2, vel, accel,
            pre2, cursor, ncursor, (float*)nullptr, 0, N);
        int spc = SLICES / nchunk; if (spc < 1) spc = 1;
        int Ec  = (E + nchunk - 1) / nchunk;
        for (int c = 0; c < nchunk; ++c) {
            int es = c * Ec;
            int ee = es + Ec; if (ee > E) ee = E;
            if (es >= ee) break;
            int* curC = cursor + (size_t)c * nb * CSTRIDE;
            int nblk = (ee - es + 256 * BIN_EPT - 1) / (256 * BIN_EPT);
            bin_kernel<<<nblk, bs, 0, stream>>>(
                nbr, rad, dirs, pre2, supp, dtp, curC, pay, cap, nb, es, ee, E);
            reduce_kernel<<<nb * spc, bs, 0, stream>>>(
                pay, curC, cap, pre2, dtp, partials, spc, c * spc, N);
        }
        fin_kernel<<<grid_n, bs, 0, stream>>>(
            area, actualArea, restDensity, dtp, partials, 0, out, N);
    } else {
        float* acc = partials;  // [N,8] at off_part
        pre_kernel<<<grid_n, bs, 0, stream>>>(
            area, actualArea, restDensity, density, pressure2, vel, accel,
            pre2, cursor, 0, acc, N * 8, N);
        edge_kernel<<<(E + bs - 1) / bs, bs, 0, stream>>>(
            nbr, rad, dirs, pre2, supp, dtp, acc, E);
        fin_kernel<<<grid_n, bs, 0, stream>>>(
            area, actualArea, restDensity, dtp, acc, 1, out, N);
    }
}